// Round 10
// baseline (360.367 us; speedup 1.0000x reference)
//
#include <hip/hip_runtime.h>
#include <stdint.h>

typedef __attribute__((ext_vector_type(8))) __bf16 bf16x8;
typedef __attribute__((ext_vector_type(4))) float f32x4;
typedef __attribute__((ext_vector_type(4))) unsigned int uint4v;
typedef __attribute__((ext_vector_type(4))) unsigned short ushort4v;
typedef __attribute__((ext_vector_type(8))) unsigned short ushort8v;

__device__ __forceinline__ float bf2f(unsigned short u){
  unsigned int x = ((unsigned int)u) << 16;
  return __builtin_bit_cast(float, x);
}
__device__ __forceinline__ unsigned short f2bf(float f){
  unsigned int x = __builtin_bit_cast(unsigned int, f);
  x += 0x7FFFu + ((x >> 16) & 1u);
  return (unsigned short)(x >> 16);
}

#define OUT_PART 4
#define OUT_PARTH 5

typedef const __attribute__((address_space(1))) unsigned int* gas1_t;
typedef __attribute__((address_space(3))) unsigned int* las3_t;
__device__ __forceinline__ void gload16(const void* g, void* l){
  __builtin_amdgcn_global_load_lds((gas1_t)g, (las3_t)l, 16, 0, 0);
}

// ---------- 128x128 tile GEMM (R7-proven) — used for g and W ----------
// C = A * Bt^T. blockIdx.z: slice = z & sMask, batch = z >> sShift.
// Register staging + double-buffered LDS, one barrier per K-step.
// LDS: row r at byte r*64; 16B-chunk p of row r holds k-chunk (p ^ ((r>>1)&3)).
template<int OM>
__global__ __launch_bounds__(256)
void gemm_bt(const unsigned short* __restrict__ A, int lda,
             const unsigned short* __restrict__ Bt, int ldb,
             int kchunk, void* __restrict__ Out, int ldo,
             size_t zStride, size_t aBatch, size_t bBatch,
             int sMask, int sShift)
{
  __shared__ uint4v AsmBuf[1024];   // 2 x 8KB
  __shared__ uint4v BsmBuf[1024];
  char* Asm = (char*)AsmBuf;
  char* Bsm = (char*)BsmBuf;

  const int tid  = threadIdx.x;
  const int lane = tid & 63;
  const int wave = tid >> 6;
  const int wy = wave >> 1, wx = wave & 1;
  const int lm = lane & 15, quad = lane >> 4;
  const int tileM = blockIdx.y * 128;
  const int tileN = blockIdx.x * 128;
  const int z = blockIdx.z;
  const int slice = z & sMask;
  const int batch = z >> sShift;

  A  += (size_t)slice*kchunk + (size_t)batch*aBatch;
  Bt += (size_t)slice*kchunk + (size_t)batch*bBatch;

  const int sr0 = tid >> 2, sc0 = tid & 3;
  const int sr1 = sr0 + 64;
  const size_t gA0 = (size_t)(tileM + sr0)*lda + ((sc0 ^ ((sr0 >> 1) & 3)) << 3);
  const size_t gA1 = (size_t)(tileM + sr1)*lda + ((sc0 ^ ((sr1 >> 1) & 3)) << 3);
  const size_t gB0 = (size_t)(tileN + sr0)*ldb + ((sc0 ^ ((sr0 >> 1) & 3)) << 3);
  const size_t gB1 = (size_t)(tileN + sr1)*ldb + ((sc0 ^ ((sr1 >> 1) & 3)) << 3);
  const int lOff0 = sr0*64 + sc0*16;
  const int lOff1 = sr1*64 + sc0*16;

  int aOff[4], bOff[4];
#pragma unroll
  for (int t = 0; t < 4; ++t){
    int ra = wy*64 + t*16 + lm;
    aOff[t] = ra*64 + ((quad ^ ((ra >> 1) & 3)) << 4);
    int rb = wx*64 + t*16 + lm;
    bOff[t] = rb*64 + ((quad ^ ((rb >> 1) & 3)) << 4);
  }

  f32x4 acc[4][4] = {};

  const int ksteps = kchunk >> 5;
  uint4v a0v = *(const uint4v*)(A + gA0);
  uint4v a1v = *(const uint4v*)(A + gA1);
  uint4v b0v = *(const uint4v*)(Bt + gB0);
  uint4v b1v = *(const uint4v*)(Bt + gB1);

  for (int kt = 0; kt < ksteps; ++kt){
    char* As = Asm + (kt & 1)*8192;
    char* Bs = Bsm + (kt & 1)*8192;
    *(uint4v*)(As + lOff0) = a0v;
    *(uint4v*)(As + lOff1) = a1v;
    *(uint4v*)(Bs + lOff0) = b0v;
    *(uint4v*)(Bs + lOff1) = b1v;
    __syncthreads();
    if (kt + 1 < ksteps){
      const unsigned short* Ak = A + (kt + 1)*32;
      const unsigned short* Bk = Bt + (kt + 1)*32;
      a0v = *(const uint4v*)(Ak + gA0);
      a1v = *(const uint4v*)(Ak + gA1);
      b0v = *(const uint4v*)(Bk + gB0);
      b1v = *(const uint4v*)(Bk + gB1);
    }
    bf16x8 af[4], bfr[4];
#pragma unroll
    for (int t = 0; t < 4; ++t){
      af[t]  = __builtin_bit_cast(bf16x8, *(const uint4v*)(As + aOff[t]));
      bfr[t] = __builtin_bit_cast(bf16x8, *(const uint4v*)(Bs + bOff[t]));
    }
#pragma unroll
    for (int tm = 0; tm < 4; ++tm)
#pragma unroll
      for (int tn = 0; tn < 4; ++tn)
        acc[tm][tn] = __builtin_amdgcn_mfma_f32_16x16x32_bf16(af[tm], bfr[tn], acc[tm][tn], 0, 0, 0);
  }

#pragma unroll
  for (int tm = 0; tm < 4; ++tm){
    const int rowb = tileM + wy*64 + tm*16 + quad*4;
#pragma unroll
    for (int tn = 0; tn < 4; ++tn){
      const int col = tileN + wx*64 + tn*16 + lm;
#pragma unroll
      for (int r = 0; r < 4; ++r){
        const float v = acc[tm][tn][r];
        const size_t idx = (size_t)z*zStride + (size_t)(rowb + r)*ldo + col;
        if (OM == OUT_PART) ((float*)Out)[idx] = v;
        else                ((unsigned short*)Out)[idx] = f2bf(v);
      }
    }
  }
}

// ---------- 128x256 tile GEMM — N in ONE tile (theta/phi, y) ----------
// R5 (verified): R3-proven structure — gload16 staging (linear LDS dest, source
// chunk pre-swizzled), counted vmcnt(6), flat ds_read/MFMA region, 2x24KB LDS.
template<int OM>
__global__ __launch_bounds__(256)
void gemm_wide(const unsigned short* __restrict__ A, int lda,
               const unsigned short* __restrict__ Bt, int ldb,
               int kchunk, void* __restrict__ Out, int ldo,
               size_t zStride, size_t aBatch, size_t bBatch,
               int sMask, int sShift)
{
  __shared__ char lds[49152];   // buf b at b*24576: A at +0 (8KB), B at +8192 (16KB)

  const int tid  = threadIdx.x;
  const int lane = tid & 63;
  const int wave = tid >> 6;
  const int wy = wave >> 1, wx = wave & 1;
  const int lm = lane & 15, quad = lane >> 4;
  const int tileM = blockIdx.y * 128;
  const int tileN = blockIdx.x * 256;
  const int z = blockIdx.z;
  const int slice = z & sMask;
  const int batch = z >> sShift;

  A  += (size_t)slice*kchunk + (size_t)batch*aBatch;
  Bt += (size_t)slice*kchunk + (size_t)batch*bBatch;

  const int srow  = tid >> 2;                               // 0..63
  const int selem = (((tid & 3) ^ ((tid >> 3) & 3)) << 3);
  const int dst   = tid << 4;
  size_t gA[2], gB[4];
#pragma unroll
  for (int i = 0; i < 2; ++i)
    gA[i] = (size_t)(tileM + srow + 64*i)*lda + selem;
#pragma unroll
  for (int i = 0; i < 4; ++i)
    gB[i] = (size_t)(tileN + srow + 64*i)*ldb + selem;

  int aOff[4], bOff[8];
#pragma unroll
  for (int t = 0; t < 4; ++t){
    const int ra = wy*64 + t*16 + lm;
    aOff[t] = ra*64 + ((quad ^ ((ra >> 1) & 3)) << 4);
  }
#pragma unroll
  for (int t = 0; t < 8; ++t){
    const int rb = wx*128 + t*16 + lm;
    bOff[t] = rb*64 + ((quad ^ ((rb >> 1) & 3)) << 4);
  }

  f32x4 acc[4][8] = {};
  const int nk = kchunk >> 5;

#pragma unroll
  for (int i = 0; i < 2; ++i) gload16(A  + gA[i], lds + i*4096 + dst);
#pragma unroll
  for (int i = 0; i < 4; ++i) gload16(Bt + gB[i], lds + 8192 + i*4096 + dst);

  for (int kt = 0; kt < nk; ++kt){
    const char* As = lds + (kt & 1)*24576;
    const char* Bs = As + 8192;
    if (kt + 1 < nk){
      char* nbuf = lds + ((kt + 1) & 1)*24576;
      const unsigned short* Ak = A  + (size_t)(kt + 1)*32;
      const unsigned short* Bk = Bt + (size_t)(kt + 1)*32;
#pragma unroll
      for (int i = 0; i < 2; ++i) gload16(Ak + gA[i], nbuf + i*4096 + dst);
#pragma unroll
      for (int i = 0; i < 4; ++i) gload16(Bk + gB[i], nbuf + 8192 + i*4096 + dst);
      asm volatile("s_waitcnt vmcnt(6)" ::: "memory");
    } else {
      asm volatile("s_waitcnt vmcnt(0)" ::: "memory");
    }
    __builtin_amdgcn_s_barrier();
    asm volatile("" ::: "memory");

    bf16x8 af[4], bfr[8];
#pragma unroll
    for (int t = 0; t < 8; ++t)
      bfr[t] = __builtin_bit_cast(bf16x8, *(const uint4v*)(Bs + bOff[t]));
#pragma unroll
    for (int t = 0; t < 4; ++t)
      af[t] = __builtin_bit_cast(bf16x8, *(const uint4v*)(As + aOff[t]));
#pragma unroll
    for (int tm = 0; tm < 4; ++tm)
#pragma unroll
      for (int tn = 0; tn < 8; ++tn)
        acc[tm][tn] = __builtin_amdgcn_mfma_f32_16x16x32_bf16(af[tm], bfr[tn], acc[tm][tn], 0, 0, 0);

    asm volatile("" ::: "memory");
    __builtin_amdgcn_s_barrier();
  }

#pragma unroll
  for (int tm = 0; tm < 4; ++tm){
    const int rowb = tileM + wy*64 + tm*16 + quad*4;
#pragma unroll
    for (int tn = 0; tn < 8; ++tn){
      const int col = tileN + wx*128 + tn*16 + lm;
#pragma unroll
      for (int r = 0; r < 4; ++r){
        const float v = acc[tm][tn][r];
        const size_t idx = (size_t)z*zStride + (size_t)(rowb + r)*ldo + col;
        if (OM == OUT_PART) ((float*)Out)[idx] = v;
        else                ((unsigned short*)Out)[idx] = f2bf(v);
      }
    }
  }
}

// ---------- 256x256 G-GEMM, 8 waves, 4-phase fine-interleave (R9) ----------
// R9: R1's harness-verified 4-phase kernel (m201-template geometry: 16 MFMA/
// phase, unit-grouped staging with phase-aligned row permutation, counted
// vmcnt, 2 barriers/phase, setprio) with ONLY the sched_barrier(0) calls
// removed. R1 post-mortem misattributed its 77us to lgkmcnt(0) — m201 itself
// uses per-phase lgkmcnt(0); the real delta vs the template was the
// sched_barrier(0) order-pinning (m141: -40% from exactly that).
// Pre-committed: if >=65us, phase-split is null at this shape -> revert to R3.
__global__ __launch_bounds__(512, 2)
void gemm_big256(const unsigned short* __restrict__ A, int lda,
                 const unsigned short* __restrict__ Bt, int ldb,
                 int K, float* __restrict__ Out, int ldo,
                 size_t aBatch, size_t bBatch, size_t oBatch)
{
  __shared__ char lds[131072];  // buf b at b*65536: A 32KB (rows' 0-255), B 32KB

  const int tid  = threadIdx.x;
  const int lane = tid & 63;
  const int wv   = tid >> 6;              // 0..7
  const int wy = wv >> 2, wx = wv & 3;    // 2 (M) x 4 (N) waves, wave tile 128x64
  const int lm = lane & 15, quad = lane >> 4;
  const int tileM = blockIdx.y * 256;
  const int tileN = blockIdx.x * 256;
  const int z = blockIdx.z;

  A   += (size_t)z*aBatch;
  Bt  += (size_t)z*bBatch;
  Out += (size_t)z*oBatch;

  // ---- staging: per unit 16KB = 2 slots x (512 thr x 16B). LDS linear dest,
  // global source row permuted per unit + chunk swizzled by (lds_row & 7).
  const int rp0 = tid >> 3;                                  // 0..63 (slot0 row')
  const int cg  = (((tid & 7) ^ ((tid >> 3) & 7)) << 3);     // swizzled k-elem off
  const int dst = tid << 4;
  // uA0 rows' 0-127 <-> global {0-63,128-191}; uA1 <-> {64-127,192-255}
  const size_t eA0[2] = { (size_t)(tileM + rp0)*lda + cg,
                          (size_t)(tileM + 128 + rp0)*lda + cg };
  const size_t eA1[2] = { (size_t)(tileM + 64 + rp0)*lda + cg,
                          (size_t)(tileM + 192 + rp0)*lda + cg };
  // uB0 rows' 0-127 <-> global {0-31 mod 64}; uB1 <-> {32-63 mod 64}
  const int rb0 = ((rp0 >> 5) << 6) + (rp0 & 31);
  const int rb1 = (((rp0 + 64) >> 5) << 6) + ((rp0 + 64) & 31);
  const size_t eB0[2] = { (size_t)(tileN + rb0)*ldb + cg,
                          (size_t)(tileN + rb1)*ldb + cg };
  const size_t eB1[2] = { (size_t)(tileN + rb0 + 32)*ldb + cg,
                          (size_t)(tileN + rb1 + 32)*ldb + cg };

  // ---- fragment read offsets (LDS row' layout; row stride 128B, 8 chunks) ----
  // A row' = wy*64 + (m&3)*16 + (m>>2)*128 + lm ; B row' = wx*32 + (n&1)*16 + (n>>1)*128 + lm
  int aR[8], bR[4], csw[2];
#pragma unroll
  for (int m = 0; m < 8; ++m)
    aR[m] = (((wy << 6) + ((m & 3) << 4) + ((m >> 2) << 7) + lm) << 7);
#pragma unroll
  for (int n = 0; n < 4; ++n)
    bR[n] = (((wx << 5) + ((n & 1) << 4) + ((n >> 1) << 7) + lm) << 7);
#pragma unroll
  for (int kk = 0; kk < 2; ++kk)
    csw[kk] = ((((kk << 2) + quad) ^ (lm & 7)) << 4);

  f32x4 acc[8][4] = {};
  const int nt = K >> 6;   // 12

  // ---- prologue: tile 0 -> buf0, issue order A0, B0, B1, A1 ----
  gload16(A  + eA0[0], lds + dst);
  gload16(A  + eA0[1], lds + 8192 + dst);
  gload16(Bt + eB0[0], lds + 32768 + dst);
  gload16(Bt + eB0[1], lds + 32768 + 8192 + dst);
  gload16(Bt + eB1[0], lds + 32768 + 16384 + dst);
  gload16(Bt + eB1[1], lds + 32768 + 16384 + 8192 + dst);
  gload16(A  + eA1[0], lds + 16384 + dst);
  gload16(A  + eA1[1], lds + 16384 + 8192 + dst);
  asm volatile("s_waitcnt vmcnt(4)" ::: "memory");   // A0,B0 landed
  __builtin_amdgcn_s_barrier();

  for (int t = 0; t < nt; ++t){
    const char* As = lds + (t & 1)*65536;
    const char* Bs = As + 32768;
    char* nxt = lds + ((t + 1) & 1)*65536;
    const bool hn = (t + 1 < nt);
    const unsigned short* An = A  + (size_t)(t + 1)*64;
    const unsigned short* Bn = Bt + (size_t)(t + 1)*64;

    bf16x8 aw[4][2], bw[4][2];

    // ---- P0: read A m0-3 + B n0-1 (12 ds_reads); stage uA0(t+1); MFMA m0-3 x n0-1
#pragma unroll
    for (int m = 0; m < 4; ++m)
#pragma unroll
      for (int kk = 0; kk < 2; ++kk)
        aw[m][kk] = __builtin_bit_cast(bf16x8, *(const uint4v*)(As + aR[m] + csw[kk]));
#pragma unroll
    for (int n = 0; n < 2; ++n)
#pragma unroll
      for (int kk = 0; kk < 2; ++kk)
        bw[n][kk] = __builtin_bit_cast(bf16x8, *(const uint4v*)(Bs + bR[n] + csw[kk]));
    if (hn){
      gload16(An + eA0[0], nxt + dst);
      gload16(An + eA0[1], nxt + 8192 + dst);
    }
    __builtin_amdgcn_s_barrier();
    asm volatile("s_waitcnt lgkmcnt(0)" ::: "memory");
    __builtin_amdgcn_s_setprio(1);
#pragma unroll
    for (int m = 0; m < 4; ++m)
#pragma unroll
      for (int n = 0; n < 2; ++n)
#pragma unroll
        for (int kk = 0; kk < 2; ++kk)
          acc[m][n] = __builtin_amdgcn_mfma_f32_16x16x32_bf16(aw[m][kk], bw[n][kk], acc[m][n], 0, 0, 0);
    __builtin_amdgcn_s_setprio(0);
    if (hn) asm volatile("s_waitcnt vmcnt(4)" ::: "memory");  // uB1(t) landed
    else    asm volatile("s_waitcnt vmcnt(2)" ::: "memory");
    __builtin_amdgcn_s_barrier();

    // ---- P1: read B n2-3 (4); stage uB0(t+1); MFMA m0-3 x n2-3
#pragma unroll
    for (int n = 2; n < 4; ++n)
#pragma unroll
      for (int kk = 0; kk < 2; ++kk)
        bw[n][kk] = __builtin_bit_cast(bf16x8, *(const uint4v*)(Bs + bR[n] + csw[kk]));
    if (hn){
      gload16(Bn + eB0[0], nxt + 32768 + dst);
      gload16(Bn + eB0[1], nxt + 32768 + 8192 + dst);
    }
    __builtin_amdgcn_s_barrier();
    asm volatile("s_waitcnt lgkmcnt(0)" ::: "memory");
    __builtin_amdgcn_s_setprio(1);
#pragma unroll
    for (int m = 0; m < 4; ++m)
#pragma unroll
      for (int n = 2; n < 4; ++n)
#pragma unroll
        for (int kk = 0; kk < 2; ++kk)
          acc[m][n] = __builtin_amdgcn_mfma_f32_16x16x32_bf16(aw[m][kk], bw[n][kk], acc[m][n], 0, 0, 0);
    __builtin_amdgcn_s_setprio(0);
    if (hn) asm volatile("s_waitcnt vmcnt(4)" ::: "memory");  // uA1(t) landed
    else    asm volatile("s_waitcnt vmcnt(0)" ::: "memory");
    __builtin_amdgcn_s_barrier();

    // ---- P2: read A m4-7 (8); stage uB1(t+1); MFMA m4-7 x n2-3
#pragma unroll
    for (int m = 0; m < 4; ++m)
#pragma unroll
      for (int kk = 0; kk < 2; ++kk)
        aw[m][kk] = __builtin_bit_cast(bf16x8, *(const uint4v*)(As + aR[m + 4] + csw[kk]));
    if (hn){
      gload16(Bn + eB1[0], nxt + 32768 + 16384 + dst);
      gload16(Bn + eB1[1], nxt + 32768 + 16384 + 8192 + dst);
    }
    __builtin_amdgcn_s_barrier();
    asm volatile("s_waitcnt lgkmcnt(0)" ::: "memory");
    __builtin_amdgcn_s_setprio(1);
#pragma unroll
    for (int m = 0; m < 4; ++m)
#pragma unroll
      for (int n = 2; n < 4; ++n)
#pragma unroll
        for (int kk = 0; kk < 2; ++kk)
          acc[m + 4][n] = __builtin_amdgcn_mfma_f32_16x16x32_bf16(aw[m][kk], bw[n][kk], acc[m + 4][n], 0, 0, 0);
    __builtin_amdgcn_s_setprio(0);
    __builtin_amdgcn_s_barrier();

    // ---- P3: no reads; stage uA1(t+1); MFMA m4-7 x n0-1 (reuses regs)
    if (hn){
      gload16(An + eA1[0], nxt + 16384 + dst);
      gload16(An + eA1[1], nxt + 16384 + 8192 + dst);
    }
    __builtin_amdgcn_s_barrier();
    __builtin_amdgcn_s_setprio(1);
#pragma unroll
    for (int m = 0; m < 4; ++m)
#pragma unroll
      for (int n = 0; n < 2; ++n)
#pragma unroll
        for (int kk = 0; kk < 2; ++kk)
          acc[m + 4][n] = __builtin_amdgcn_mfma_f32_16x16x32_bf16(aw[m][kk], bw[n][kk], acc[m + 4][n], 0, 0, 0);
    __builtin_amdgcn_s_setprio(0);
    if (hn) asm volatile("s_waitcnt vmcnt(4)" ::: "memory");  // uA0,uB0(t+1) landed
    __builtin_amdgcn_s_barrier();
  }

#pragma unroll
  for (int tm = 0; tm < 8; ++tm){
    const int rowb = tileM + wy*128 + tm*16 + quad*4;
#pragma unroll
    for (int tn = 0; tn < 4; ++tn){
      const int col = tileN + wx*64 + tn*16 + lm;
#pragma unroll
      for (int r = 0; r < 4; ++r)
        Out[(size_t)(rowb + r)*ldo + col] = acc[tm][tn][r];
    }
  }
}

// ---------- dedicated reduces (R6: 16B-vectorized, verified) ----------
__global__ __launch_bounds__(256)
void reduce_tp(const float* __restrict__ part,
               const float* __restrict__ tb, const float* __restrict__ pb,
               unsigned short* __restrict__ th, unsigned short* __restrict__ ph)
{
  const size_t i4 = ((size_t)blockIdx.x*256 + threadIdx.x) * 4;   // grid 4096
  const int which = (int)(i4 >> 21);
  const size_t j = i4 & 0x1FFFFFu;          // multiple of 4
  const int col = (int)(j & 255u);
  f32x4 v = {0.f, 0.f, 0.f, 0.f};
#pragma unroll
  for (int s = 0; s < 4; ++s){
    f32x4 p = *(const f32x4*)&part[(size_t)((which << 2) + s)*2097152 + j];
#pragma unroll
    for (int e = 0; e < 4; ++e) v[e] += p[e];
  }
  f32x4 bv = *(const f32x4*)&(which ? pb : tb)[col];
  ushort4v hi, lo;
#pragma unroll
  for (int e = 0; e < 4; ++e){
    const float t = v[e] + bv[e];
    hi[e] = f2bf(t);
    lo[e] = f2bf(t - bf2f(hi[e]));
  }
  const size_t o = (j >> 8)*768 + col;
  unsigned short* O = which ? ph : th;
  const int dup = which ? 512 : 256;
  const int loo = which ? 256 : 512;
  *(ushort4v*)&O[o] = hi;
  *(ushort4v*)&O[o + dup] = hi;
  *(ushort4v*)&O[o + loo] = lo;
}

__global__ __launch_bounds__(256)
void reduce_g(const unsigned short* __restrict__ part,
              const float* __restrict__ gb, unsigned short* __restrict__ gs)
{
  const size_t i8 = ((size_t)blockIdx.x*256 + threadIdx.x) * 8;   // grid 1024
  float v[8] = {};
#pragma unroll
  for (int s = 0; s < 4; ++s){
    uint4v u = *(const uint4v*)&part[(size_t)s*2097152 + i8];
#pragma unroll
    for (int e = 0; e < 8; ++e)
      v[e] += bf2f((unsigned short)((e & 1) ? (u[e >> 1] >> 16) : (u[e >> 1] & 0xffffu)));
  }
  const float gbv = gb[i8 >> 13];
  ushort8v o;
#pragma unroll
  for (int e = 0; e < 8; ++e) o[e] = f2bf(v[e] + gbv);
  *(ushort8v*)&gs[i8] = o;
}

__global__ __launch_bounds__(256)
void reduce_y(const unsigned short* __restrict__ part,
              unsigned short* __restrict__ yb)
{
  const size_t i8 = ((size_t)blockIdx.x*256 + threadIdx.x) * 8;   // grid 1024
  const int b = (int)(i8 >> 20);
  const size_t j = i8 & 0xFFFFFu;
  float v[8] = {};
#pragma unroll
  for (int s = 0; s < 8; ++s){
    uint4v u = *(const uint4v*)&part[(size_t)((b << 3) + s)*1048576 + j];
#pragma unroll
    for (int e = 0; e < 8; ++e)
      v[e] += bf2f((unsigned short)((e & 1) ? (u[e >> 1] >> 16) : (u[e >> 1] & 0xffffu)));
  }
  ushort8v o;
#pragma unroll
  for (int e = 0; e < 8; ++e) o[e] = f2bf(v[e]);
  *(ushort8v*)&yb[i8] = o;
}

__global__ __launch_bounds__(256)
void reduce_w(const float* __restrict__ part, const float* __restrict__ wb,
              void* __restrict__ Out, const unsigned int* __restrict__ flagPtr)
{
  const size_t i4 = ((size_t)blockIdx.x*256 + threadIdx.x) * 4;   // grid 4096
  const int b = (int)(i4 >> 21);
  const size_t j = i4 & 0x1FFFFFu;
  f32x4 p0 = *(const f32x4*)&part[(size_t)(b << 1)*2097152 + j];
  f32x4 p1 = *(const f32x4*)&part[(size_t)((b << 1) | 1)*2097152 + j];
  const float w = wb[(i4 >> 12) & 511u];
  f32x4 v;
#pragma unroll
  for (int e = 0; e < 4; ++e) v[e] = p0[e] + p1[e] + w;
  if (flagPtr[0]){
    *(f32x4*)&((float*)Out)[i4] = v;
  } else {
    ushort4v o;
#pragma unroll
    for (int e = 0; e < 4; ++e) o[e] = f2bf(v[e]);
    *(ushort4v*)&((unsigned short*)Out)[i4] = o;
  }
}

// dtype vote + scalar/bias canonicalization (f32 canon)
__global__ __launch_bounds__(256)
void detect_prep(const void* __restrict__ content,
                 const void* tb, const void* pb, const void* gb, const void* wb,
                 const void* sc,
                 unsigned int* __restrict__ flag, float* __restrict__ scale_c,
                 float* tb_c, float* pb_c, float* gb_c, float* wb_c)
{
  __shared__ int cnt;
  __shared__ unsigned int flg;
  const int tid = threadIdx.x;
  if (tid == 0) cnt = 0;
  __syncthreads();
  unsigned int w = ((const unsigned int*)content)[tid];
  int e = (w >> 23) & 0xFF;
  if (e >= 0x70 && e <= 0x8F) atomicAdd(&cnt, 1);
  __syncthreads();
  if (tid == 0){ flg = (cnt >= 128) ? 1u : 0u; flag[0] = flg; }
  __syncthreads();
  const unsigned int f = flg;
  auto rd = [&](const void* p, int i)->float{
    return f ? ((const float*)p)[i] : bf2f(((const unsigned short*)p)[i]);
  };
  if (tid < 9) scale_c[tid] = rd(sc, tid);
  tb_c[tid] = rd(tb, tid);
  pb_c[tid] = rd(pb, tid);
  gb_c[tid] = rd(gb, tid);
  wb_c[tid] = rd(wb, tid);
  wb_c[tid + 256] = rd(wb, tid + 256);
}

// canonicalize weights: theta/phi -> wdup rows [whi(512)|wlo(512)|whi(512)],
// g_w -> gwc bf16, W_w -> wwc bf16
__global__ __launch_bounds__(256)
void conv_weights(const void* tw, const void* pw, const void* gw, const void* www,
                  const unsigned int* __restrict__ flagPtr,
                  unsigned short* __restrict__ wdup,
                  unsigned short* __restrict__ gwc,
                  unsigned short* __restrict__ wwc)
{
  const unsigned int fl = flagPtr[0];
  const int sec = blockIdx.y;
  const int idx = blockIdx.x*256 + threadIdx.x;
  auto rd = [&](const void* p, int i)->float{
    return fl ? ((const float*)p)[i] : bf2f(((const unsigned short*)p)[i]);
  };
  if (sec < 2){
    const void* w = sec ? pw : tw;
    const int o = idx >> 9, c = idx & 511;
    float v = rd(w, o*512 + c);
    unsigned short hi = f2bf(v);
    unsigned short lo = f2bf(v - bf2f(hi));
    unsigned short* base = wdup + (size_t)sec*256*1536 + o*1536;
    base[c] = hi; base[512 + c] = lo; base[1024 + c] = hi;
  } else if (sec == 2){
    const int o = idx >> 9, c = idx & 511;
    gwc[o*512 + c] = f2bf(rd(gw, o*512 + c));
  } else {
    const int o = idx >> 8, c = idx & 255;
    wwc[o*256 + c] = f2bf(rd(www, o*256 + c));
  }
}

// per-(b,c) mean / invstd over 4096 spatial elems; z picks content/style
__global__ __launch_bounds__(256)
void stats_all(const void* __restrict__ content, const void* __restrict__ style,
               const unsigned int* __restrict__ flagPtr,
               float* __restrict__ statsC, float* __restrict__ statsS)
{
  const unsigned int fl = flagPtr[0];
  const void* X = blockIdx.z ? style : content;
  float* stats = blockIdx.z ? statsS : statsC;
  const int bc = blockIdx.x;
  const int tid = threadIdx.x;
  float s = 0.f, q = 0.f;
  if (fl){
    const f32x4* row = (const f32x4*)((const float*)X + (size_t)bc*4096);
#pragma unroll
    for (int i = 0; i < 4; ++i){
      f32x4 v = row[tid + i*256];
#pragma unroll
      for (int j = 0; j < 4; ++j){ s += v[j]; q += v[j]*v[j]; }
    }
  } else {
    const uint4v* row = (const uint4v*)((const unsigned short*)X + (size_t)bc*4096);
#pragma unroll
    for (int i = 0; i < 2; ++i){
      uint4v u = row[tid + i*256];
#pragma unroll
      for (int j = 0; j < 4; ++j){
        float a = bf2f((unsigned short)(u[j] & 0xffffu));
        float b = bf2f((unsigned short)(u[j] >> 16));
        s += a + b; q += a*a + b*b;
      }
    }
  }
#pragma unroll
  for (int off = 32; off > 0; off >>= 1){
    s += __shfl_down(s, off);
    q += __shfl_down(q, off);
  }
  __shared__ float rs[4], rq[4];
  if ((tid & 63) == 0){ rs[tid >> 6] = s; rq[tid >> 6] = q; }
  __syncthreads();
  if (tid == 0){
    s = rs[0] + rs[1] + rs[2] + rs[3];
    q = rq[0] + rq[1] + rq[2] + rq[3];
    float mean = s * (1.0f/4096.0f);
    float var  = (q - 4096.0f*mean*mean) * (1.0f/4095.0f);
    stats[bc*2 + 0] = mean;
    stats[bc*2 + 1] = 1.0f / sqrtf(var + 1e-5f);
  }
}

// (c,l)->(l,c) transpose, all tensors+batches in one dispatch.
__global__ __launch_bounds__(256)
void norm_all(const void* __restrict__ content, const void* __restrict__ style,
              const void* __restrict__ fusion,
              const float* __restrict__ statsC, const float* __restrict__ statsS,
              unsigned short* __restrict__ xn, unsigned short* __restrict__ sn,
              unsigned short* __restrict__ fst,
              const unsigned int* __restrict__ flagPtr)
{
  __shared__ float tile[64][65];
  const unsigned int fl = flagPtr[0];
  const int z = blockIdx.z;
  const int which = z >> 1;
  const int b  = z & 1;
  const int l0 = blockIdx.x * 64;
  const int c0 = blockIdx.y * 64;
  const int tid = threadIdx.x;
  const int tx = tid & 63, ty = tid >> 6;

  const void* X = which == 0 ? content : (which == 1 ? style : fusion);
#pragma unroll
  for (int p = 0; p < 16; ++p){
    const int cc = ty + p*4;
    const size_t src = ((size_t)b*512 + c0 + cc)*4096 + l0 + tx;
    tile[cc][tx] = fl ? ((const float*)X)[src]
                      : bf2f(((const unsigned short*)X)[src]);
  }
  __syncthreads();
  if (which < 2){
    const float* stats = which ? statsS : statsC;
    const float mean = stats[(b*512 + c0 + tx)*2 + 0];
    const float inv  = stats[(b*512 + c0 + tx)*2 + 1];
    unsigned short* Out = which ? sn : xn;
#pragma unroll
    for (int p = 0; p < 16; ++p){
      const int lj = ty + p*4;
      const float v = (tile[tx][lj] - mean) * inv;
      const size_t o = ((size_t)b*4096 + l0 + lj)*1536 + c0 + tx;
      const unsigned short hi = f2bf(v);
      Out[o] = hi;
      Out[o + 512] = hi;
      Out[o + 1024] = f2bf(v - bf2f(hi));
    }
  } else {
#pragma unroll
    for (int p = 0; p < 16; ++p){
      const int lj = ty + p*4;
      const size_t o = ((size_t)b*4096 + l0 + lj)*512 + c0 + tx;
      fst[o] = f2bf(tile[tx][lj]);
    }
  }
}

// f[l,m] = sum s^2 * G[refl_l, refl_m]; rowwise softmax; both batches.
// R4 (verified, best): XCD-contiguous swizzle + hoisted x-clamps; thread-strided
// m = lane-consecutive coalesced loads (R7's consecutive-m remap REVERTED).
__global__ __launch_bounds__(256)
void softmax_rows(const float* __restrict__ Gbase, const float* __restrict__ scale_c,
                  unsigned short* __restrict__ Pbase)
{
  const int bid = (int)((blockIdx.x & 7)*1024 + (blockIdx.x >> 3));  // XCD swizzle
  const int bb = bid >> 12;
  const int l  = bid & 4095;
  const float* G = Gbase + (size_t)bb*16777216;
  unsigned short* P = Pbase + (size_t)bb*16777216;
  const int yy = l >> 6, xx = l & 63;
  const int tid = threadIdx.x;

  float s2[9];
  const float* rowp[9];
#pragma unroll
  for (int di = 0; di < 3; ++di){
    int ry = yy + di - 1; ry = ry < 0 ? 1 : (ry > 63 ? 62 : ry);
#pragma unroll
    for (int dj = 0; dj < 3; ++dj){
      int rx = xx + dj - 1; rx = rx < 0 ? 1 : (rx > 63 ? 62 : rx);
      const int k = di*3 + dj;
      const float s = scale_c[k];
      s2[k] = s*s;
      rowp[k] = G + (size_t)(ry*64 + rx)*4096;
    }
  }

  const int mxo = tid & 63, my0 = tid >> 6;
  int cx[3];
#pragma unroll
  for (int d = 0; d < 3; ++d){
    int t1 = mxo + d - 1;
    cx[d] = (t1 < 0 ? 1 : (t1 > 63 ? 62 : t1));
  }

  float fv[16];
  float mx = -3.0e38f;
#pragma unroll
  for (int i = 0; i < 16; ++i){
    const int my = my0 + i*4;
    int cy[3];
#pragma unroll
    for (int d = 0; d < 3; ++d){
      int t0 = my + d - 1;
      cy[d] = (t0 < 0 ? 1 : (t0 > 63 ? 62 : t0))*64;
    }
    float v = 0.f;
#pragma unroll
    for (int di = 0; di < 3; ++di)
#pragma unroll
      for (int dj = 0; dj < 3; ++dj)
        v = fmaf(s2[di*3+dj], rowp[di*3+dj][cy[di] + cx[dj]], v);
    fv[i] = v;
    mx = fmaxf(mx, v);
  }

  __shared__ float redA[4], redB[4];
#pragma unroll
  for (int off = 32; off > 0; off >>= 1) mx = fmaxf(mx, __shfl_down(mx, off));
  if ((tid & 63) == 0) redA[tid >> 6] = mx;
  __syncthreads();
  mx = fmaxf(fmaxf(redA[0], redA[1]), fmaxf(redA[2], redA[3]));

  float sum = 0.f;
#pragma unroll
  for (int i = 0; i < 16; ++i){ fv[i] = __expf(fv[i] - mx); sum += fv[i]; }
#pragma unroll
  for (int off = 32; off > 0; off >>= 1) sum += __shfl_down(sum, off);
  if ((tid & 63) == 0) redB[tid >> 6] = sum;
  __syncthreads();
  sum = redB[0] + redB[1] + redB[2] + redB[3];
  const float inv = 1.0f / sum;

  unsigned short* Prow = P + (size_t)l*4096;
#pragma unroll
  for (int i = 0; i < 16; ++i) Prow[tid + i*256] = f2bf(fv[i]*inv);
}

extern "C" void kernel_launch(void* const* d_in, const int* in_sizes, int n_in,
                              void* d_out, int out_size, void* d_ws, size_t ws_size,
                              hipStream_t stream)
{
  const void* content = d_in[0];
  const void* style   = d_in[1];
  const void* fusion  = d_in[2];
  const void* theta_w = d_in[3];
  const void* theta_b = d_in[4];
  const void* phi_w   = d_in[5];
  const void* phi_b   = d_in[6];
  const void* g_w     = d_in[7];
  const void* g_b     = d_in[8];
  const void* W_w     = d_in[9];
  const void* W_b     = d_in[10];
  const void* scale   = d_in[11];

  char* ws = (char*)d_ws;
  size_t off = 0;
  auto take = [&](size_t bytes)->char*{
    char* p = ws + off; off += (bytes + 255) & ~(size_t)255; return p;
  };

  unsigned int* flag  = (unsigned int*)take(256);
  float* scale_c      = (float*)take(256);
  float* tb_c         = (float*)take(1024);
  float* pb_c         = (float*)take(1024);
  float* gb_c         = (float*)take(1024);
  float* wb_c         = (float*)take(2048);
  float* statsC       = (float*)take(1024ull*2*4);
  float* statsS       = (float*)take(1024ull*2*4);
  unsigned short* wdup = (unsigned short*)take(2ull*256*1536*2); // theta|phi [hi|lo|hi]
  unsigned short* gwc  = (unsigned short*)take(256ull*512*2);
  unsigned short* wwc  = (unsigned short*)take(512ull*256*2);
  unsigned short* th   = (unsigned short*)take(8192ull*768*2);   // [hi|hi|lo]
  unsigned short* ph   = (unsigned short*)take(8192ull*768*2);   // [hi|lo|hi]
  unsigned short* gs   = (unsigned short*)take(256ull*8192*2);   // [o][b*4096+m]
  unsigned short* yb   = (unsigned short*)take(2ull*4096*256*2); // [b][l][o]
  float* G0            = (float*)take(4096ull*4096*4);           // batch 0
  float* G1            = (float*)take(4096ull*4096*4);           // batch 1
  char* unionC         = take(64ull*1024*1024);                  // 64MB
  unsigned short* xn   = (unsigned short*)unionC;                       // 24MB
  unsigned short* sn   = (unsigned short*)(unionC + 8192ull*1536*2);    // 24MB
  unsigned short* fst  = (unsigned short*)(unionC + 2ull*8192*1536*2);  // 8MB
  unsigned short* P    = (unsigned short*)unionC;  // phase2: 2x32MB, overlays xn/sn/fst

  // partial overlays (dead-G windows):
  float* partTP          = G0;                    // 8 x 8MB f32 (theta|phi)
  unsigned short* partG  = (unsigned short*)G1;   // 4 x 4MB bf16
  unsigned short* partY  = (unsigned short*)G0;   // 16 x 2MB bf16 (after softmax)
  float* partW           = G1;                    // 4 x 8MB f32 (after reduce_y)

  detect_prep<<<1, 256, 0, stream>>>(content, theta_b, phi_b, g_b, W_b, scale,
                                     flag, scale_c, tb_c, pb_c, gb_c, wb_c);
  conv_weights<<<dim3(512,4), 256, 0, stream>>>(theta_w, phi_w, g_w, W_w, flag,
                                                wdup, gwc, wwc);
  stats_all<<<dim3(1024,1,2), 256, 0, stream>>>(content, style, flag, statsC, statsS);
  norm_all<<<dim3(64,8,6), 256, 0, stream>>>(content, style, fusion,
                                             statsC, statsS, xn, sn, fst, flag);

  // theta+phi: (8192x256) x2 = [xn|sn] * wdup^T; N=256 in ONE tile (gemm_wide),
  // z: which = z>>2, slice = z&3 (kchunk 384); partials f32 in G0.
  gemm_wide<OUT_PART><<<dim3(1,64,8), 256, 0, stream>>>(
      xn, 1536, wdup, 1536, 384, partTP, 256, 8192ull*256,
      8192ull*1536, 256ull*1536, 3, 2);
  reduce_tp<<<4096, 256, 0, stream>>>(partTP, tb_c, pb_c, th, ph);

  // g: (256x8192) = gwc(256x512) * fst(8192x512)^T, split-K 4x128, bf16 in G1.
  gemm_bt<OUT_PARTH><<<dim3(64,2,4), 256, 0, stream>>>(
      gwc, 512, fst, 512, 128, partG, 8192, 256ull*8192, 0, 0, 3, 2);
  reduce_g<<<1024, 256, 0, stream>>>(partG, gb_c, gs);

  // G = th * ph^T (f32), K=768, both batches, 256x256 tile,
  // 4-phase fine-interleave, no sched_barrier (R9).
  gemm_big256<<<dim3(16,16,2), 512, 0, stream>>>(
      th, 768, ph, 768, 768, G0, 4096,
      4096ull*768, 4096ull*768, (size_t)(G1 - G0));

  // f-assembly + softmax, both batches -> P (overlays xn/sn/fst).
  softmax_rows<<<8192, 256, 0, stream>>>(G0, scale_c, P);

  // y = P * gs_b^T : (4096x256) x2; N=256 in ONE tile (gemm_wide),
  // z: b = z>>3, slice = z&7 (kchunk 512); bf16 partials in G0 (dead).
  gemm_wide<OUT_PARTH><<<dim3(1,32,16), 256, 0, stream>>>(
      P, 4096, gs, 8192, 512, partY, 256, 4096ull*256,
      16777216ull, 4096ull, 7, 3);
  reduce_y<<<1024, 256, 0, stream>>>(partY, yb);

  // out = wwc(512x256) * yb_b(4096x256)^T + W_b : z: b = z>>1, slice = z&1
  // (kchunk 128); f32 partials in G1 (dead after reduce_y).
  gemm_bt<OUT_PART><<<dim3(32,4,4), 256, 0, stream>>>(
      wwc, 256, yb, 256, 128, partW, 4096, 512ull*4096,
      0, 4096ull*256, 1, 1);
  reduce_w<<<4096, 256, 0, stream>>>(partW, wb_c, d_out, flag);
}

// Round 11
// 357.688 us; speedup vs baseline: 1.0075x; 1.0075x over previous
//
#include <hip/hip_runtime.h>
#include <stdint.h>

typedef __attribute__((ext_vector_type(8))) __bf16 bf16x8;
typedef __attribute__((ext_vector_type(4))) float f32x4;
typedef __attribute__((ext_vector_type(4))) unsigned int uint4v;
typedef __attribute__((ext_vector_type(4))) unsigned short ushort4v;
typedef __attribute__((ext_vector_type(8))) unsigned short ushort8v;

__device__ __forceinline__ float bf2f(unsigned short u){
  unsigned int x = ((unsigned int)u) << 16;
  return __builtin_bit_cast(float, x);
}
__device__ __forceinline__ unsigned short f2bf(float f){
  unsigned int x = __builtin_bit_cast(unsigned int, f);
  x += 0x7FFFu + ((x >> 16) & 1u);
  return (unsigned short)(x >> 16);
}

#define OUT_PART 4
#define OUT_PARTH 5

typedef const __attribute__((address_space(1))) unsigned int* gas1_t;
typedef __attribute__((address_space(3))) unsigned int* las3_t;
__device__ __forceinline__ void gload16(const void* g, void* l){
  __builtin_amdgcn_global_load_lds((gas1_t)g, (las3_t)l, 16, 0, 0);
}

// ---------- 128x128 tile GEMM (R7-proven) — used for g and W ----------
// C = A * Bt^T. blockIdx.z: slice = z & sMask, batch = z >> sShift.
// Register staging + double-buffered LDS, one barrier per K-step.
// LDS: row r at byte r*64; 16B-chunk p of row r holds k-chunk (p ^ ((r>>1)&3)).
template<int OM>
__global__ __launch_bounds__(256)
void gemm_bt(const unsigned short* __restrict__ A, int lda,
             const unsigned short* __restrict__ Bt, int ldb,
             int kchunk, void* __restrict__ Out, int ldo,
             size_t zStride, size_t aBatch, size_t bBatch,
             int sMask, int sShift)
{
  __shared__ uint4v AsmBuf[1024];   // 2 x 8KB
  __shared__ uint4v BsmBuf[1024];
  char* Asm = (char*)AsmBuf;
  char* Bsm = (char*)BsmBuf;

  const int tid  = threadIdx.x;
  const int lane = tid & 63;
  const int wave = tid >> 6;
  const int wy = wave >> 1, wx = wave & 1;
  const int lm = lane & 15, quad = lane >> 4;
  const int tileM = blockIdx.y * 128;
  const int tileN = blockIdx.x * 128;
  const int z = blockIdx.z;
  const int slice = z & sMask;
  const int batch = z >> sShift;

  A  += (size_t)slice*kchunk + (size_t)batch*aBatch;
  Bt += (size_t)slice*kchunk + (size_t)batch*bBatch;

  const int sr0 = tid >> 2, sc0 = tid & 3;
  const int sr1 = sr0 + 64;
  const size_t gA0 = (size_t)(tileM + sr0)*lda + ((sc0 ^ ((sr0 >> 1) & 3)) << 3);
  const size_t gA1 = (size_t)(tileM + sr1)*lda + ((sc0 ^ ((sr1 >> 1) & 3)) << 3);
  const size_t gB0 = (size_t)(tileN + sr0)*ldb + ((sc0 ^ ((sr0 >> 1) & 3)) << 3);
  const size_t gB1 = (size_t)(tileN + sr1)*ldb + ((sc0 ^ ((sr1 >> 1) & 3)) << 3);
  const int lOff0 = sr0*64 + sc0*16;
  const int lOff1 = sr1*64 + sc0*16;

  int aOff[4], bOff[4];
#pragma unroll
  for (int t = 0; t < 4; ++t){
    int ra = wy*64 + t*16 + lm;
    aOff[t] = ra*64 + ((quad ^ ((ra >> 1) & 3)) << 4);
    int rb = wx*64 + t*16 + lm;
    bOff[t] = rb*64 + ((quad ^ ((rb >> 1) & 3)) << 4);
  }

  f32x4 acc[4][4] = {};

  const int ksteps = kchunk >> 5;
  uint4v a0v = *(const uint4v*)(A + gA0);
  uint4v a1v = *(const uint4v*)(A + gA1);
  uint4v b0v = *(const uint4v*)(Bt + gB0);
  uint4v b1v = *(const uint4v*)(Bt + gB1);

  for (int kt = 0; kt < ksteps; ++kt){
    char* As = Asm + (kt & 1)*8192;
    char* Bs = Bsm + (kt & 1)*8192;
    *(uint4v*)(As + lOff0) = a0v;
    *(uint4v*)(As + lOff1) = a1v;
    *(uint4v*)(Bs + lOff0) = b0v;
    *(uint4v*)(Bs + lOff1) = b1v;
    __syncthreads();
    if (kt + 1 < ksteps){
      const unsigned short* Ak = A + (kt + 1)*32;
      const unsigned short* Bk = Bt + (kt + 1)*32;
      a0v = *(const uint4v*)(Ak + gA0);
      a1v = *(const uint4v*)(Ak + gA1);
      b0v = *(const uint4v*)(Bk + gB0);
      b1v = *(const uint4v*)(Bk + gB1);
    }
    bf16x8 af[4], bfr[4];
#pragma unroll
    for (int t = 0; t < 4; ++t){
      af[t]  = __builtin_bit_cast(bf16x8, *(const uint4v*)(As + aOff[t]));
      bfr[t] = __builtin_bit_cast(bf16x8, *(const uint4v*)(Bs + bOff[t]));
    }
#pragma unroll
    for (int tm = 0; tm < 4; ++tm)
#pragma unroll
      for (int tn = 0; tn < 4; ++tn)
        acc[tm][tn] = __builtin_amdgcn_mfma_f32_16x16x32_bf16(af[tm], bfr[tn], acc[tm][tn], 0, 0, 0);
  }

#pragma unroll
  for (int tm = 0; tm < 4; ++tm){
    const int rowb = tileM + wy*64 + tm*16 + quad*4;
#pragma unroll
    for (int tn = 0; tn < 4; ++tn){
      const int col = tileN + wx*64 + tn*16 + lm;
#pragma unroll
      for (int r = 0; r < 4; ++r){
        const float v = acc[tm][tn][r];
        const size_t idx = (size_t)z*zStride + (size_t)(rowb + r)*ldo + col;
        if (OM == OUT_PART) ((float*)Out)[idx] = v;
        else                ((unsigned short*)Out)[idx] = f2bf(v);
      }
    }
  }
}

// ---------- 128x256 tile GEMM — N in ONE tile (theta/phi, y) ----------
// R5 (verified): R3-proven structure — gload16 staging (linear LDS dest, source
// chunk pre-swizzled), counted vmcnt(6), flat ds_read/MFMA region, 2x24KB LDS.
template<int OM>
__global__ __launch_bounds__(256)
void gemm_wide(const unsigned short* __restrict__ A, int lda,
               const unsigned short* __restrict__ Bt, int ldb,
               int kchunk, void* __restrict__ Out, int ldo,
               size_t zStride, size_t aBatch, size_t bBatch,
               int sMask, int sShift)
{
  __shared__ char lds[49152];   // buf b at b*24576: A at +0 (8KB), B at +8192 (16KB)

  const int tid  = threadIdx.x;
  const int lane = tid & 63;
  const int wave = tid >> 6;
  const int wy = wave >> 1, wx = wave & 1;
  const int lm = lane & 15, quad = lane >> 4;
  const int tileM = blockIdx.y * 128;
  const int tileN = blockIdx.x * 256;
  const int z = blockIdx.z;
  const int slice = z & sMask;
  const int batch = z >> sShift;

  A  += (size_t)slice*kchunk + (size_t)batch*aBatch;
  Bt += (size_t)slice*kchunk + (size_t)batch*bBatch;

  const int srow  = tid >> 2;                               // 0..63
  const int selem = (((tid & 3) ^ ((tid >> 3) & 3)) << 3);
  const int dst   = tid << 4;
  size_t gA[2], gB[4];
#pragma unroll
  for (int i = 0; i < 2; ++i)
    gA[i] = (size_t)(tileM + srow + 64*i)*lda + selem;
#pragma unroll
  for (int i = 0; i < 4; ++i)
    gB[i] = (size_t)(tileN + srow + 64*i)*ldb + selem;

  int aOff[4], bOff[8];
#pragma unroll
  for (int t = 0; t < 4; ++t){
    const int ra = wy*64 + t*16 + lm;
    aOff[t] = ra*64 + ((quad ^ ((ra >> 1) & 3)) << 4);
  }
#pragma unroll
  for (int t = 0; t < 8; ++t){
    const int rb = wx*128 + t*16 + lm;
    bOff[t] = rb*64 + ((quad ^ ((rb >> 1) & 3)) << 4);
  }

  f32x4 acc[4][8] = {};
  const int nk = kchunk >> 5;

#pragma unroll
  for (int i = 0; i < 2; ++i) gload16(A  + gA[i], lds + i*4096 + dst);
#pragma unroll
  for (int i = 0; i < 4; ++i) gload16(Bt + gB[i], lds + 8192 + i*4096 + dst);

  for (int kt = 0; kt < nk; ++kt){
    const char* As = lds + (kt & 1)*24576;
    const char* Bs = As + 8192;
    if (kt + 1 < nk){
      char* nbuf = lds + ((kt + 1) & 1)*24576;
      const unsigned short* Ak = A  + (size_t)(kt + 1)*32;
      const unsigned short* Bk = Bt + (size_t)(kt + 1)*32;
#pragma unroll
      for (int i = 0; i < 2; ++i) gload16(Ak + gA[i], nbuf + i*4096 + dst);
#pragma unroll
      for (int i = 0; i < 4; ++i) gload16(Bk + gB[i], nbuf + 8192 + i*4096 + dst);
      asm volatile("s_waitcnt vmcnt(6)" ::: "memory");
    } else {
      asm volatile("s_waitcnt vmcnt(0)" ::: "memory");
    }
    __builtin_amdgcn_s_barrier();
    asm volatile("" ::: "memory");

    bf16x8 af[4], bfr[8];
#pragma unroll
    for (int t = 0; t < 8; ++t)
      bfr[t] = __builtin_bit_cast(bf16x8, *(const uint4v*)(Bs + bOff[t]));
#pragma unroll
    for (int t = 0; t < 4; ++t)
      af[t] = __builtin_bit_cast(bf16x8, *(const uint4v*)(As + aOff[t]));
#pragma unroll
    for (int tm = 0; tm < 4; ++tm)
#pragma unroll
      for (int tn = 0; tn < 8; ++tn)
        acc[tm][tn] = __builtin_amdgcn_mfma_f32_16x16x32_bf16(af[tm], bfr[tn], acc[tm][tn], 0, 0, 0);

    asm volatile("" ::: "memory");
    __builtin_amdgcn_s_barrier();
  }

#pragma unroll
  for (int tm = 0; tm < 4; ++tm){
    const int rowb = tileM + wy*64 + tm*16 + quad*4;
#pragma unroll
    for (int tn = 0; tn < 8; ++tn){
      const int col = tileN + wx*128 + tn*16 + lm;
#pragma unroll
      for (int r = 0; r < 4; ++r){
        const float v = acc[tm][tn][r];
        const size_t idx = (size_t)z*zStride + (size_t)(rowb + r)*ldo + col;
        if (OM == OUT_PART) ((float*)Out)[idx] = v;
        else                ((unsigned short*)Out)[idx] = f2bf(v);
      }
    }
  }
}

// ---------- 256x256 G-GEMM, 8 waves, BK=64 flat region + counted vmcnt ----------
// R3/R10 FINAL (best of 5 structures: 67.0-67.6us across 3 runs): ONE
// barrier-pair + ONE counted vmcnt(8) per 64-K, 128KB LDS dbuf, flat region
// (plain ds_reads + MFMAs -> compiler emits counted lgkmcnt itself).
// Refuted alternatives: coarse-split (72.5), serialized 4-phase (77.4),
// BK=32 flat (69.9), 4-phase minus sched_barrier (68.3, R9) -> phase-split
// is null at this shape (K=768, 1 block/CU, f32 out). Chunked XCD swizzle
// kept (FETCH/perf-neutral, R6).
__global__ __launch_bounds__(512, 2)
void gemm_big256(const unsigned short* __restrict__ A, int lda,
                 const unsigned short* __restrict__ Bt, int ldb,
                 int K, float* __restrict__ Out, int ldo,
                 size_t aBatch, size_t bBatch, size_t oBatch)
{
  __shared__ char lds[131072];  // buf b at b*65536: A 32KB (256 rows x 128B), B 32KB

  const int tid  = threadIdx.x;
  const int lane = tid & 63;
  const int wv   = tid >> 6;              // 0..7
  const int wy = wv >> 2, wx = wv & 3;    // 2 (M) x 4 (N) waves, wave tile 128x64
  const int lm = lane & 15, quad = lane >> 4;

  const int lid = (int)(blockIdx.x + (blockIdx.y << 4) + (blockIdx.z << 8));
  const int swz = ((lid & 7) << 6) + (lid >> 3);
  const int tileM = ((swz >> 4) & 15) * 256;
  const int tileN = (swz & 15) * 256;
  const int z = swz >> 8;

  A   += (size_t)z*aBatch;
  Bt  += (size_t)z*bBatch;
  Out += (size_t)z*oBatch;

  const int srow  = tid >> 3;                               // 0..63
  const int selem = (((tid & 7) ^ ((tid >> 3) & 7)) << 3);  // element offset
  const int dst   = tid << 4;
  size_t gA[4], gB[4];
#pragma unroll
  for (int i = 0; i < 4; ++i){
    gA[i] = (size_t)(tileM + srow + 64*i)*lda + selem;
    gB[i] = (size_t)(tileN + srow + 64*i)*ldb + selem;
  }

  int xq[2];
#pragma unroll
  for (int kk = 0; kk < 2; ++kk)
    xq[kk] = ((((kk << 2) + quad) ^ (lm & 7)) << 4);
  const int aBase = (wy*128 + lm) << 7;   // + m*2048, m=0..7
  const int bBase = (wx*64  + lm) << 7;   // + n*2048, n=0..3

  f32x4 acc[8][4] = {};
  const int nk = K >> 6;   // 12

#pragma unroll
  for (int i = 0; i < 4; ++i) gload16(A  + gA[i], lds + i*8192 + dst);
#pragma unroll
  for (int i = 0; i < 4; ++i) gload16(Bt + gB[i], lds + 32768 + i*8192 + dst);

  for (int kt = 0; kt < nk; ++kt){
    const char* As = lds + (kt & 1)*65536;
    const char* Bs = As + 32768;
    if (kt + 1 < nk){
      char* nbuf = lds + ((kt + 1) & 1)*65536;
      const unsigned short* Ak = A  + (size_t)(kt + 1)*64;
      const unsigned short* Bk = Bt + (size_t)(kt + 1)*64;
#pragma unroll
      for (int i = 0; i < 4; ++i) gload16(Ak + gA[i], nbuf + i*8192 + dst);
#pragma unroll
      for (int i = 0; i < 4; ++i) gload16(Bk + gB[i], nbuf + 32768 + i*8192 + dst);
      asm volatile("s_waitcnt vmcnt(8)" ::: "memory");
    } else {
      asm volatile("s_waitcnt vmcnt(0)" ::: "memory");
    }
    __builtin_amdgcn_s_barrier();
    asm volatile("" ::: "memory");

#pragma unroll
    for (int kk = 0; kk < 2; ++kk){
      bf16x8 af[8], bfr[4];
#pragma unroll
      for (int n = 0; n < 4; ++n)
        bfr[n] = __builtin_bit_cast(bf16x8, *(const uint4v*)(Bs + bBase + n*2048 + xq[kk]));
#pragma unroll
      for (int m = 0; m < 8; ++m)
        af[m] = __builtin_bit_cast(bf16x8, *(const uint4v*)(As + aBase + m*2048 + xq[kk]));
#pragma unroll
      for (int m = 0; m < 8; ++m)
#pragma unroll
        for (int n = 0; n < 4; ++n)
          acc[m][n] = __builtin_amdgcn_mfma_f32_16x16x32_bf16(af[m], bfr[n], acc[m][n], 0, 0, 0);
    }

    asm volatile("" ::: "memory");
    __builtin_amdgcn_s_barrier();
  }

#pragma unroll
  for (int tm = 0; tm < 8; ++tm){
    const int rowb = tileM + wy*128 + tm*16 + quad*4;
#pragma unroll
    for (int tn = 0; tn < 4; ++tn){
      const int col = tileN + wx*64 + tn*16 + lm;
#pragma unroll
      for (int r = 0; r < 4; ++r)
        Out[(size_t)(rowb + r)*ldo + col] = acc[tm][tn][r];
    }
  }
}

// ---------- dedicated reduces (R6: 16B-vectorized, verified) ----------
__global__ __launch_bounds__(256)
void reduce_tp(const float* __restrict__ part,
               const float* __restrict__ tb, const float* __restrict__ pb,
               unsigned short* __restrict__ th, unsigned short* __restrict__ ph)
{
  const size_t i4 = ((size_t)blockIdx.x*256 + threadIdx.x) * 4;   // grid 4096
  const int which = (int)(i4 >> 21);
  const size_t j = i4 & 0x1FFFFFu;          // multiple of 4
  const int col = (int)(j & 255u);
  f32x4 v = {0.f, 0.f, 0.f, 0.f};
#pragma unroll
  for (int s = 0; s < 4; ++s){
    f32x4 p = *(const f32x4*)&part[(size_t)((which << 2) + s)*2097152 + j];
#pragma unroll
    for (int e = 0; e < 4; ++e) v[e] += p[e];
  }
  f32x4 bv = *(const f32x4*)&(which ? pb : tb)[col];
  ushort4v hi, lo;
#pragma unroll
  for (int e = 0; e < 4; ++e){
    const float t = v[e] + bv[e];
    hi[e] = f2bf(t);
    lo[e] = f2bf(t - bf2f(hi[e]));
  }
  const size_t o = (j >> 8)*768 + col;
  unsigned short* O = which ? ph : th;
  const int dup = which ? 512 : 256;
  const int loo = which ? 256 : 512;
  *(ushort4v*)&O[o] = hi;
  *(ushort4v*)&O[o + dup] = hi;
  *(ushort4v*)&O[o + loo] = lo;
}

__global__ __launch_bounds__(256)
void reduce_g(const unsigned short* __restrict__ part,
              const float* __restrict__ gb, unsigned short* __restrict__ gs)
{
  const size_t i8 = ((size_t)blockIdx.x*256 + threadIdx.x) * 8;   // grid 1024
  float v[8] = {};
#pragma unroll
  for (int s = 0; s < 4; ++s){
    uint4v u = *(const uint4v*)&part[(size_t)s*2097152 + i8];
#pragma unroll
    for (int e = 0; e < 8; ++e)
      v[e] += bf2f((unsigned short)((e & 1) ? (u[e >> 1] >> 16) : (u[e >> 1] & 0xffffu)));
  }
  const float gbv = gb[i8 >> 13];
  ushort8v o;
#pragma unroll
  for (int e = 0; e < 8; ++e) o[e] = f2bf(v[e] + gbv);
  *(ushort8v*)&gs[i8] = o;
}

__global__ __launch_bounds__(256)
void reduce_y(const unsigned short* __restrict__ part,
              unsigned short* __restrict__ yb)
{
  const size_t i8 = ((size_t)blockIdx.x*256 + threadIdx.x) * 8;   // grid 1024
  const int b = (int)(i8 >> 20);
  const size_t j = i8 & 0xFFFFFu;
  float v[8] = {};
#pragma unroll
  for (int s = 0; s < 8; ++s){
    uint4v u = *(const uint4v*)&part[(size_t)((b << 3) + s)*1048576 + j];
#pragma unroll
    for (int e = 0; e < 8; ++e)
      v[e] += bf2f((unsigned short)((e & 1) ? (u[e >> 1] >> 16) : (u[e >> 1] & 0xffffu)));
  }
  ushort8v o;
#pragma unroll
  for (int e = 0; e < 8; ++e) o[e] = f2bf(v[e]);
  *(ushort8v*)&yb[i8] = o;
}

__global__ __launch_bounds__(256)
void reduce_w(const float* __restrict__ part, const float* __restrict__ wb,
              void* __restrict__ Out, const unsigned int* __restrict__ flagPtr)
{
  const size_t i4 = ((size_t)blockIdx.x*256 + threadIdx.x) * 4;   // grid 4096
  const int b = (int)(i4 >> 21);
  const size_t j = i4 & 0x1FFFFFu;
  f32x4 p0 = *(const f32x4*)&part[(size_t)(b << 1)*2097152 + j];
  f32x4 p1 = *(const f32x4*)&part[(size_t)((b << 1) | 1)*2097152 + j];
  const float w = wb[(i4 >> 12) & 511u];
  f32x4 v;
#pragma unroll
  for (int e = 0; e < 4; ++e) v[e] = p0[e] + p1[e] + w;
  if (flagPtr[0]){
    *(f32x4*)&((float*)Out)[i4] = v;
  } else {
    ushort4v o;
#pragma unroll
    for (int e = 0; e < 4; ++e) o[e] = f2bf(v[e]);
    *(ushort4v*)&((unsigned short*)Out)[i4] = o;
  }
}

// dtype vote + scalar/bias canonicalization (f32 canon)
__global__ __launch_bounds__(256)
void detect_prep(const void* __restrict__ content,
                 const void* tb, const void* pb, const void* gb, const void* wb,
                 const void* sc,
                 unsigned int* __restrict__ flag, float* __restrict__ scale_c,
                 float* tb_c, float* pb_c, float* gb_c, float* wb_c)
{
  __shared__ int cnt;
  __shared__ unsigned int flg;
  const int tid = threadIdx.x;
  if (tid == 0) cnt = 0;
  __syncthreads();
  unsigned int w = ((const unsigned int*)content)[tid];
  int e = (w >> 23) & 0xFF;
  if (e >= 0x70 && e <= 0x8F) atomicAdd(&cnt, 1);
  __syncthreads();
  if (tid == 0){ flg = (cnt >= 128) ? 1u : 0u; flag[0] = flg; }
  __syncthreads();
  const unsigned int f = flg;
  auto rd = [&](const void* p, int i)->float{
    return f ? ((const float*)p)[i] : bf2f(((const unsigned short*)p)[i]);
  };
  if (tid < 9) scale_c[tid] = rd(sc, tid);
  tb_c[tid] = rd(tb, tid);
  pb_c[tid] = rd(pb, tid);
  gb_c[tid] = rd(gb, tid);
  wb_c[tid] = rd(wb, tid);
  wb_c[tid + 256] = rd(wb, tid + 256);
}

// canonicalize weights: theta/phi -> wdup rows [whi(512)|wlo(512)|whi(512)],
// g_w -> gwc bf16, W_w -> wwc bf16
__global__ __launch_bounds__(256)
void conv_weights(const void* tw, const void* pw, const void* gw, const void* www,
                  const unsigned int* __restrict__ flagPtr,
                  unsigned short* __restrict__ wdup,
                  unsigned short* __restrict__ gwc,
                  unsigned short* __restrict__ wwc)
{
  const unsigned int fl = flagPtr[0];
  const int sec = blockIdx.y;
  const int idx = blockIdx.x*256 + threadIdx.x;
  auto rd = [&](const void* p, int i)->float{
    return fl ? ((const float*)p)[i] : bf2f(((const unsigned short*)p)[i]);
  };
  if (sec < 2){
    const void* w = sec ? pw : tw;
    const int o = idx >> 9, c = idx & 511;
    float v = rd(w, o*512 + c);
    unsigned short hi = f2bf(v);
    unsigned short lo = f2bf(v - bf2f(hi));
    unsigned short* base = wdup + (size_t)sec*256*1536 + o*1536;
    base[c] = hi; base[512 + c] = lo; base[1024 + c] = hi;
  } else if (sec == 2){
    const int o = idx >> 9, c = idx & 511;
    gwc[o*512 + c] = f2bf(rd(gw, o*512 + c));
  } else {
    const int o = idx >> 8, c = idx & 255;
    wwc[o*256 + c] = f2bf(rd(www, o*256 + c));
  }
}

// per-(b,c) mean / invstd over 4096 spatial elems; z picks content/style
__global__ __launch_bounds__(256)
void stats_all(const void* __restrict__ content, const void* __restrict__ style,
               const unsigned int* __restrict__ flagPtr,
               float* __restrict__ statsC, float* __restrict__ statsS)
{
  const unsigned int fl = flagPtr[0];
  const void* X = blockIdx.z ? style : content;
  float* stats = blockIdx.z ? statsS : statsC;
  const int bc = blockIdx.x;
  const int tid = threadIdx.x;
  float s = 0.f, q = 0.f;
  if (fl){
    const f32x4* row = (const f32x4*)((const float*)X + (size_t)bc*4096);
#pragma unroll
    for (int i = 0; i < 4; ++i){
      f32x4 v = row[tid + i*256];
#pragma unroll
      for (int j = 0; j < 4; ++j){ s += v[j]; q += v[j]*v[j]; }
    }
  } else {
    const uint4v* row = (const uint4v*)((const unsigned short*)X + (size_t)bc*4096);
#pragma unroll
    for (int i = 0; i < 2; ++i){
      uint4v u = row[tid + i*256];
#pragma unroll
      for (int j = 0; j < 4; ++j){
        float a = bf2f((unsigned short)(u[j] & 0xffffu));
        float b = bf2f((unsigned short)(u[j] >> 16));
        s += a + b; q += a*a + b*b;
      }
    }
  }
#pragma unroll
  for (int off = 32; off > 0; off >>= 1){
    s += __shfl_down(s, off);
    q += __shfl_down(q, off);
  }
  __shared__ float rs[4], rq[4];
  if ((tid & 63) == 0){ rs[tid >> 6] = s; rq[tid >> 6] = q; }
  __syncthreads();
  if (tid == 0){
    s = rs[0] + rs[1] + rs[2] + rs[3];
    q = rq[0] + rq[1] + rq[2] + rq[3];
    float mean = s * (1.0f/4096.0f);
    float var  = (q - 4096.0f*mean*mean) * (1.0f/4095.0f);
    stats[bc*2 + 0] = mean;
    stats[bc*2 + 1] = 1.0f / sqrtf(var + 1e-5f);
  }
}

// (c,l)->(l,c) transpose, all tensors+batches in one dispatch.
__global__ __launch_bounds__(256)
void norm_all(const void* __restrict__ content, const void* __restrict__ style,
              const void* __restrict__ fusion,
              const float* __restrict__ statsC, const float* __restrict__ statsS,
              unsigned short* __restrict__ xn, unsigned short* __restrict__ sn,
              unsigned short* __restrict__ fst,
              const unsigned int* __restrict__ flagPtr)
{
  __shared__ float tile[64][65];
  const unsigned int fl = flagPtr[0];
  const int z = blockIdx.z;
  const int which = z >> 1;
  const int b  = z & 1;
  const int l0 = blockIdx.x * 64;
  const int c0 = blockIdx.y * 64;
  const int tid = threadIdx.x;
  const int tx = tid & 63, ty = tid >> 6;

  const void* X = which == 0 ? content : (which == 1 ? style : fusion);
#pragma unroll
  for (int p = 0; p < 16; ++p){
    const int cc = ty + p*4;
    const size_t src = ((size_t)b*512 + c0 + cc)*4096 + l0 + tx;
    tile[cc][tx] = fl ? ((const float*)X)[src]
                      : bf2f(((const unsigned short*)X)[src]);
  }
  __syncthreads();
  if (which < 2){
    const float* stats = which ? statsS : statsC;
    const float mean = stats[(b*512 + c0 + tx)*2 + 0];
    const float inv  = stats[(b*512 + c0 + tx)*2 + 1];
    unsigned short* Out = which ? sn : xn;
#pragma unroll
    for (int p = 0; p < 16; ++p){
      const int lj = ty + p*4;
      const float v = (tile[tx][lj] - mean) * inv;
      const size_t o = ((size_t)b*4096 + l0 + lj)*1536 + c0 + tx;
      const unsigned short hi = f2bf(v);
      Out[o] = hi;
      Out[o + 512] = hi;
      Out[o + 1024] = f2bf(v - bf2f(hi));
    }
  } else {
#pragma unroll
    for (int p = 0; p < 16; ++p){
      const int lj = ty + p*4;
      const size_t o = ((size_t)b*4096 + l0 + lj)*512 + c0 + tx;
      fst[o] = f2bf(tile[tx][lj]);
    }
  }
}

// f[l,m] = sum s^2 * G[refl_l, refl_m]; rowwise softmax; both batches.
// R4 (verified, best): XCD-contiguous swizzle + hoisted x-clamps; thread-strided
// m = lane-consecutive coalesced loads (R7's consecutive-m remap REVERTED).
__global__ __launch_bounds__(256)
void softmax_rows(const float* __restrict__ Gbase, const float* __restrict__ scale_c,
                  unsigned short* __restrict__ Pbase)
{
  const int bid = (int)((blockIdx.x & 7)*1024 + (blockIdx.x >> 3));  // XCD swizzle
  const int bb = bid >> 12;
  const int l  = bid & 4095;
  const float* G = Gbase + (size_t)bb*16777216;
  unsigned short* P = Pbase + (size_t)bb*16777216;
  const int yy = l >> 6, xx = l & 63;
  const int tid = threadIdx.x;

  float s2[9];
  const float* rowp[9];
#pragma unroll
  for (int di = 0; di < 3; ++di){
    int ry = yy + di - 1; ry = ry < 0 ? 1 : (ry > 63 ? 62 : ry);
#pragma unroll
    for (int dj = 0; dj < 3; ++dj){
      int rx = xx + dj - 1; rx = rx < 0 ? 1 : (rx > 63 ? 62 : rx);
      const int k = di*3 + dj;
      const float s = scale_c[k];
      s2[k] = s*s;
      rowp[k] = G + (size_t)(ry*64 + rx)*4096;
    }
  }

  const int mxo = tid & 63, my0 = tid >> 6;
  int cx[3];
#pragma unroll
  for (int d = 0; d < 3; ++d){
    int t1 = mxo + d - 1;
    cx[d] = (t1 < 0 ? 1 : (t1 > 63 ? 62 : t1));
  }

  float fv[16];
  float mx = -3.0e38f;
#pragma unroll
  for (int i = 0; i < 16; ++i){
    const int my = my0 + i*4;
    int cy[3];
#pragma unroll
    for (int d = 0; d < 3; ++d){
      int t0 = my + d - 1;
      cy[d] = (t0 < 0 ? 1 : (t0 > 63 ? 62 : t0))*64;
    }
    float v = 0.f;
#pragma unroll
    for (int di = 0; di < 3; ++di)
#pragma unroll
      for (int dj = 0; dj < 3; ++dj)
        v = fmaf(s2[di*3+dj], rowp[di*3+dj][cy[di] + cx[dj]], v);
    fv[i] = v;
    mx = fmaxf(mx, v);
  }

  __shared__ float redA[4], redB[4];
#pragma unroll
  for (int off = 32; off > 0; off >>= 1) mx = fmaxf(mx, __shfl_down(mx, off));
  if ((tid & 63) == 0) redA[tid >> 6] = mx;
  __syncthreads();
  mx = fmaxf(fmaxf(redA[0], redA[1]), fmaxf(redA[2], redA[3]));

  float sum = 0.f;
#pragma unroll
  for (int i = 0; i < 16; ++i){ fv[i] = __expf(fv[i] - mx); sum += fv[i]; }
#pragma unroll
  for (int off = 32; off > 0; off >>= 1) sum += __shfl_down(sum, off);
  if ((tid & 63) == 0) redB[tid >> 6] = sum;
  __syncthreads();
  sum = redB[0] + redB[1] + redB[2] + redB[3];
  const float inv = 1.0f / sum;

  unsigned short* Prow = P + (size_t)l*4096;
#pragma unroll
  for (int i = 0; i < 16; ++i) Prow[tid + i*256] = f2bf(fv[i]*inv);
}

extern "C" void kernel_launch(void* const* d_in, const int* in_sizes, int n_in,
                              void* d_out, int out_size, void* d_ws, size_t ws_size,
                              hipStream_t stream)
{
  const void* content = d_in[0];
  const void* style   = d_in[1];
  const void* fusion  = d_in[2];
  const void* theta_w = d_in[3];
  const void* theta_b = d_in[4];
  const void* phi_w   = d_in[5];
  const void* phi_b   = d_in[6];
  const void* g_w     = d_in[7];
  const void* g_b     = d_in[8];
  const void* W_w     = d_in[9];
  const void* W_b     = d_in[10];
  const void* scale   = d_in[11];

  char* ws = (char*)d_ws;
  size_t off = 0;
  auto take = [&](size_t bytes)->char*{
    char* p = ws + off; off += (bytes + 255) & ~(size_t)255; return p;
  };

  unsigned int* flag  = (unsigned int*)take(256);
  float* scale_c      = (float*)take(256);
  float* tb_c         = (float*)take(1024);
  float* pb_c         = (float*)take(1024);
  float* gb_c         = (float*)take(1024);
  float* wb_c         = (float*)take(2048);
  float* statsC       = (float*)take(1024ull*2*4);
  float* statsS       = (float*)take(1024ull*2*4);
  unsigned short* wdup = (unsigned short*)take(2ull*256*1536*2); // theta|phi [hi|lo|hi]
  unsigned short* gwc  = (unsigned short*)take(256ull*512*2);
  unsigned short* wwc  = (unsigned short*)take(512ull*256*2);
  unsigned short* th   = (unsigned short*)take(8192ull*768*2);   // [hi|hi|lo]
  unsigned short* ph   = (unsigned short*)take(8192ull*768*2);   // [hi|lo|hi]
  unsigned short* gs   = (unsigned short*)take(256ull*8192*2);   // [o][b*4096+m]
  unsigned short* yb   = (unsigned short*)take(2ull*4096*256*2); // [b][l][o]
  float* G0            = (float*)take(4096ull*4096*4);           // batch 0
  float* G1            = (float*)take(4096ull*4096*4);           // batch 1
  char* unionC         = take(64ull*1024*1024);                  // 64MB
  unsigned short* xn   = (unsigned short*)unionC;                       // 24MB
  unsigned short* sn   = (unsigned short*)(unionC + 8192ull*1536*2);    // 24MB
  unsigned short* fst  = (unsigned short*)(unionC + 2ull*8192*1536*2);  // 8MB
  unsigned short* P    = (unsigned short*)unionC;  // phase2: 2x32MB, overlays xn/sn/fst

  // partial overlays (dead-G windows):
  float* partTP          = G0;                    // 8 x 8MB f32 (theta|phi)
  unsigned short* partG  = (unsigned short*)G1;   // 4 x 4MB bf16
  unsigned short* partY  = (unsigned short*)G0;   // 16 x 2MB bf16 (after softmax)
  float* partW           = G1;                    // 4 x 8MB f32 (after reduce_y)

  detect_prep<<<1, 256, 0, stream>>>(content, theta_b, phi_b, g_b, W_b, scale,
                                     flag, scale_c, tb_c, pb_c, gb_c, wb_c);
  conv_weights<<<dim3(512,4), 256, 0, stream>>>(theta_w, phi_w, g_w, W_w, flag,
                                                wdup, gwc, wwc);
  stats_all<<<dim3(1024,1,2), 256, 0, stream>>>(content, style, flag, statsC, statsS);
  norm_all<<<dim3(64,8,6), 256, 0, stream>>>(content, style, fusion,
                                             statsC, statsS, xn, sn, fst, flag);

  // theta+phi: (8192x256) x2 = [xn|sn] * wdup^T; N=256 in ONE tile (gemm_wide),
  // z: which = z>>2, slice = z&3 (kchunk 384); partials f32 in G0.
  gemm_wide<OUT_PART><<<dim3(1,64,8), 256, 0, stream>>>(
      xn, 1536, wdup, 1536, 384, partTP, 256, 8192ull*256,
      8192ull*1536, 256ull*1536, 3, 2);
  reduce_tp<<<4096, 256, 0, stream>>>(partTP, tb_c, pb_c, th, ph);

  // g: (256x8192) = gwc(256x512) * fst(8192x512)^T, split-K 4x128, bf16 in G1.
  gemm_bt<OUT_PARTH><<<dim3(64,2,4), 256, 0, stream>>>(
      gwc, 512, fst, 512, 128, partG, 8192, 256ull*8192, 0, 0, 3, 2);
  reduce_g<<<1024, 256, 0, stream>>>(partG, gb_c, gs);

  // G = th * ph^T (f32), K=768, both batches, 256x256 tile,
  // BK=64 flat region + counted vmcnt(8) (R3 final) + chunked XCD swizzle.
  gemm_big256<<<dim3(16,16,2), 512, 0, stream>>>(
      th, 768, ph, 768, 768, G0, 4096,
      4096ull*768, 4096ull*768, (size_t)(G1 - G0));

  // f-assembly + softmax, both batches -> P (overlays xn/sn/fst).
  softmax_rows<<<8192, 256, 0, stream>>>(G0, scale_c, P);

  // y = P * gs_b^T : (4096x256) x2; N=256 in ONE tile (gemm_wide),
  // z: b = z>>3, slice = z&7 (kchunk 512); bf16 partials in G0 (dead).
  gemm_wide<OUT_PARTH><<<dim3(1,32,16), 256, 0, stream>>>(
      P, 4096, gs, 8192, 512, partY, 256, 4096ull*256,
      16777216ull, 4096ull, 7, 3);
  reduce_y<<<1024, 256, 0, stream>>>(partY, yb);

  // out = wwc(512x256) * yb_b(4096x256)^T + W_b : z: b = z>>1, slice = z&1
  // (kchunk 128); f32 partials in G1 (dead after reduce_y).
  gemm_bt<OUT_PART><<<dim3(32,4,4), 256, 0, stream>>>(
      wwc, 256, yb, 256, 128, partW, 4096, 512ull*4096,
      0, 4096ull*256, 1, 1);
  reduce_w<<<4096, 256, 0, stream>>>(partW, wb_c, d_out, flag);
}